// Round 14
// baseline (413.449 us; speedup 1.0000x reference)
//
#include <hip/hip_runtime.h>

// AssociationLayer: masked Sinkhorn (100 iters) + mutual-argmax assignment.
// R19 = R18 + 4-way MFMA chain split (second notch of confirmed mechanism).
//  R18 post-mortem: 2-way split 255.8 -> 247.2 us (-3.4%), matching the
//  chain-latency prediction (save ~68cyc x2 x100 ~= 5.7us; measured 8).
//  Cost: ~15 MB whisper-spill from +8 transient VGPRs (WRITE 200->215) --
//  outweighed. R19 deepens to 4 independent 2-deep chains per direction:
//  predicted +~2.8us if the allocator absorbs +16 transient accs; spill
//  tripwire = WRITE_SIZE > 260 MB -> revert to R18 as final.
//  All other levers evidence-closed (see R13-R17 trail in git journal):
//  >64-Vreg panels spill; AGPR residency copies/spills; VALU dir2 loses;
//  2 barriers/iter = bipartite minimum; cross-wave sums at one atomic.
//  Structure (unchanged): 1024 thr/16 waves; dir1 MFMA KA-regs + v bcast;
//  dir2 MFMA with lane-linear KTL (stride-1 b128, 0 conflicts); ping-pong
//  Su/Sv LDS atomics; bitwise-consistent epilogue; 16B packed stores.
//  absmax ~1.0 (tie-flip class) vs threshold 4.92.

#define T_MAX   256
#define L_FLAT  (257 * 257)
#define N_ITERS 100
#define LAMBDA_F 10.0f
#define EPS_F    1e-12f

#define ROR1 0x121
#define ROR2 0x122
#define ROR4 0x124
#define ROR8 0x128

typedef short bf8   __attribute__((ext_vector_type(8)));  // 8 bf16 = 4 VGPRs
typedef float f32x4 __attribute__((ext_vector_type(4)));

struct F4 { float a, b, c, d; };   // 16B payload, 4B-aligned packed store

template<int CTRL>
__device__ __forceinline__ float dpp_addf(float x) {
    int t = __builtin_amdgcn_update_dpp(0, __float_as_int(x), CTRL, 0xF, 0xF, true);
    return x + __int_as_float(t);
}
__device__ __forceinline__ float swz16_addf(float x) {
    return x + __int_as_float(__builtin_amdgcn_ds_swizzle(__float_as_int(x), 0x401F));
}
__device__ __forceinline__ float swz16_maxf(float x) {
    return fmaxf(x, __int_as_float(__builtin_amdgcn_ds_swizzle(__float_as_int(x), 0x401F)));
}
__device__ __forceinline__ int swz16_ori(int x) {
    return x | __builtin_amdgcn_ds_swizzle(x, 0x401F);
}
__device__ __forceinline__ float fast_rcp(float x) {
#if __has_builtin(__builtin_amdgcn_rcpf)
    return __builtin_amdgcn_rcpf(x);
#else
    return 1.0f / x;
#endif
}
__device__ __forceinline__ unsigned short f2bf(float x) {   // RNE f32->bf16
    unsigned u = __float_as_uint(x);
    return (unsigned short)((u + 0x7FFFu + ((u >> 16) & 1u)) >> 16);
}
__device__ __forceinline__ float bf2f(short s) {            // exact bf16->f32
    return __uint_as_float(((unsigned)(unsigned short)s) << 16);
}

__global__ __launch_bounds__(1024, 1) void assoc_sinkhorn_kernel(
    const float* __restrict__ aff,
    const int*   __restrict__ ndet,
    const int*   __restrict__ ntrk,
    float*       __restrict__ out_t,
    float*       __restrict__ out_a)
{
    const int b   = blockIdx.x;
    const int nd  = ndet[b];
    const int nt  = ntrk[b];
    const int tid = threadIdx.x;
    const int w   = tid >> 6;     // wave 0..15 -> rows/cols 16w..16w+15
    const int l   = tid & 63;
    const int lr  = l & 15;       // m/n index within 16x16 tile
    const int lk  = l >> 4;       // k-group 0..3

    // K^T fragment-linear: [w][t][lane][8 bf16] -> 16B/lane, stride-1 b128
    __shared__ __align__(16) unsigned short KTL[16 * 8 * 64 * 8];   // 128 KB
    __shared__ __align__(16) unsigned short u_bf[256];
    __shared__ __align__(16) unsigned short v_bf[256];
    __shared__ __align__(16) float u_f[256];
    __shared__ __align__(16) float v_f[256];
    __shared__ __align__(16) float SuAcc[2];   // ping-pong cross-wave sums
    __shared__ __align__(16) float SvAcc[2];
    __shared__ __align__(16) float rm_s[256];
    __shared__ __align__(16) float cm_s[256];

    const float ndf = (float)nd;
    const float ntf = (float)nt;

    // ---------------- prologue: build bf16 K fragments ----------------
    bf8 KA[8];   // row-panel (A-op): row 16w+lr, cols 32t+8lk+j
    const float* Ab = aff + (size_t)b * (T_MAX * T_MAX);

    const int myrow = 16 * w + lr;
    const int mycol = 16 * w + lr;
    unsigned short* myKTL = &KTL[(size_t)(w * 8 * 64 + l) * 8];   // + t*512

    {
        const bool rv = (myrow < nt);
        const float* rp = Ab + (size_t)myrow * T_MAX;
        #pragma unroll
        for (int t = 0; t < 8; ++t) {
            const int c0 = 32 * t + 8 * lk;
            const float4 x0 = *reinterpret_cast<const float4*>(rp + c0);
            const float4 x1 = *reinterpret_cast<const float4*>(rp + c0 + 4);
            const float e[8] = {x0.x, x0.y, x0.z, x0.w, x1.x, x1.y, x1.z, x1.w};
            bf8 kk;
            #pragma unroll
            for (int j = 0; j < 8; ++j) {
                const float val = (rv && (c0 + j) < nd) ? __expf(LAMBDA_F * e[j]) : 0.0f;
                kk[j] = (short)f2bf(val);
            }
            KA[t] = kk;
        }
    }
    {
        // col-panel (B-op): col 16w+lr, rows 32t+8lk+j -> straight to LDS
        const bool cv = (mycol < nd);
        #pragma unroll
        for (int t = 0; t < 8; ++t) {
            const int r0 = 32 * t + 8 * lk;
            bf8 kk;
            #pragma unroll
            for (int j = 0; j < 8; ++j) {
                const float x = Ab[(size_t)(r0 + j) * T_MAX + mycol];
                const float val = (cv && (r0 + j) < nt) ? __expf(LAMBDA_F * x) : 0.0f;
                kk[j] = (short)f2bf(val);
            }
            *reinterpret_cast<bf8*>(myKTL + t * 512) = kk;   // lane-linear b128
        }
    }

    if (tid < 256) v_bf[tid] = (tid < nd) ? f2bf(1.0f) : (unsigned short)0;
    if (tid == 0) {
        SuAcc[0] = 0.0f; SuAcc[1] = 0.0f;
        SvAcc[0] = ndf;  SvAcc[1] = 0.0f;   // initial Sv = nd (v=1 on valid cols)
    }
    __syncthreads();

    float vbd = 1.0f;   // v[nd]
    float ubd = 0.0f;   // u[nt]

    const int r_a0 = 16 * w + 4 * lk;   // base row of this lane's acc quad
    float u4[4] = {0.f, 0.f, 0.f, 0.f};
    float v0 = 0.0f;

    // loop-invariant validity masks (mul instead of cmp+cndmask in loop)
    float rvm[4];
    #pragma unroll
    for (int q = 0; q < 4; ++q) rvm[q] = ((r_a0 + q) < nt) ? 1.0f : 0.0f;
    const float cvm = (mycol < nd) ? 1.0f : 0.0f;

    // ---------------- Sinkhorn iterations ----------------
    for (int it = 0; it < N_ITERS; ++it) {
        const int p = it & 1;
        const float Sv = SvAcc[p];   // broadcast read; consumed below (slack)

        // ---- dir1: p = K @ v -- FOUR independent 2-deep MFMA chains ----
        f32x4 a0 = {0.f, 0.f, 0.f, 0.f};
        f32x4 a1 = {0.f, 0.f, 0.f, 0.f};
        f32x4 a2 = {0.f, 0.f, 0.f, 0.f};
        f32x4 a3 = {0.f, 0.f, 0.f, 0.f};
        #pragma unroll
        for (int t = 0; t < 2; ++t) {
            const bf8 V0 = *reinterpret_cast<const bf8*>(&v_bf[32 * (4 * t)     + 8 * lk]);
            const bf8 V1 = *reinterpret_cast<const bf8*>(&v_bf[32 * (4 * t + 1) + 8 * lk]);
            const bf8 V2 = *reinterpret_cast<const bf8*>(&v_bf[32 * (4 * t + 2) + 8 * lk]);
            const bf8 V3 = *reinterpret_cast<const bf8*>(&v_bf[32 * (4 * t + 3) + 8 * lk]);
            a0 = __builtin_amdgcn_mfma_f32_16x16x32_bf16(KA[4 * t],     V0, a0, 0, 0, 0);
            a1 = __builtin_amdgcn_mfma_f32_16x16x32_bf16(KA[4 * t + 1], V1, a1, 0, 0, 0);
            a2 = __builtin_amdgcn_mfma_f32_16x16x32_bf16(KA[4 * t + 2], V2, a2, 0, 0, 0);
            a3 = __builtin_amdgcn_mfma_f32_16x16x32_bf16(KA[4 * t + 3], V3, a3, 0, 0, 0);
        }

        const float vbdE = vbd + EPS_F;
        #pragma unroll
        for (int q = 0; q < 4; ++q)
            u4[q] = rvm[q] * fast_rcp(((a0[q] + a1[q]) + (a2[q] + a3[q])) + vbdE);

        // wave Sigma(u): sum 4 quads, fold lk groups (x16, x32), one atomic
        {
            float su = (u4[0] + u4[1]) + (u4[2] + u4[3]);
            su = swz16_addf(su);
            su += __shfl_xor(su, 32, 64);
            if (l == 0) atomicAdd(&SuAcc[p], su);
        }
        if (tid == 0) SuAcc[p ^ 1] = 0.0f;   // stale slot: last read prev iter

        // publish u as bf16; writers: lr==0 lanes (4 rows each)
        if (lr == 0) {
            const unsigned p01 = (unsigned)f2bf(u4[0]) | ((unsigned)f2bf(u4[1]) << 16);
            const unsigned p23 = (unsigned)f2bf(u4[2]) | ((unsigned)f2bf(u4[3]) << 16);
            *reinterpret_cast<uint2*>(&u_bf[r_a0]) = uint2{p01, p23};
        }
        __syncthreads();   // barrier A: u + SuAcc[p] published

        const float Su = SuAcc[p];   // one broadcast read
        const float ubd_new = ndf * fast_rcp(Sv + vbd + EPS_F);
        const float vbd_new = ntf * fast_rcp(Su + ubd_new + EPS_F);

        // ---- dir2: q = K^T @ u -- FOUR independent 2-deep MFMA chains ----
        f32x4 q0 = {0.f, 0.f, 0.f, 0.f};
        f32x4 q1 = {0.f, 0.f, 0.f, 0.f};
        f32x4 q2 = {0.f, 0.f, 0.f, 0.f};
        f32x4 q3 = {0.f, 0.f, 0.f, 0.f};
        #pragma unroll
        for (int t = 0; t < 2; ++t) {
            const bf8 U0 = *reinterpret_cast<const bf8*>(&u_bf[32 * (4 * t)     + 8 * lk]);
            const bf8 U1 = *reinterpret_cast<const bf8*>(&u_bf[32 * (4 * t + 1) + 8 * lk]);
            const bf8 U2 = *reinterpret_cast<const bf8*>(&u_bf[32 * (4 * t + 2) + 8 * lk]);
            const bf8 U3 = *reinterpret_cast<const bf8*>(&u_bf[32 * (4 * t + 3) + 8 * lk]);
            const bf8 k0 = *reinterpret_cast<const bf8*>(myKTL + (4 * t)     * 512);
            const bf8 k1 = *reinterpret_cast<const bf8*>(myKTL + (4 * t + 1) * 512);
            const bf8 k2 = *reinterpret_cast<const bf8*>(myKTL + (4 * t + 2) * 512);
            const bf8 k3 = *reinterpret_cast<const bf8*>(myKTL + (4 * t + 3) * 512);
            q0 = __builtin_amdgcn_mfma_f32_16x16x32_bf16(U0, k0, q0, 0, 0, 0);
            q1 = __builtin_amdgcn_mfma_f32_16x16x32_bf16(U1, k1, q1, 0, 0, 0);
            q2 = __builtin_amdgcn_mfma_f32_16x16x32_bf16(U2, k2, q2, 0, 0, 0);
            q3 = __builtin_amdgcn_mfma_f32_16x16x32_bf16(U3, k3, q3, 0, 0, 0);
        }

        const float ubdE = ubd_new + EPS_F;
        v0 = cvm * fast_rcp(((q0[0] + q1[0]) + (q2[0] + q3[0])) + ubdE);

        // wave Sigma(v) over its 16 cols (varies over lr): DPP fold + atomic
        {
            float sv = v0;
            sv = dpp_addf<ROR1>(sv);
            sv = dpp_addf<ROR2>(sv);
            sv = dpp_addf<ROR4>(sv);
            sv = dpp_addf<ROR8>(sv);
            if (l == 0) atomicAdd(&SvAcc[p ^ 1], sv);
        }
        if (tid == 0) SvAcc[p] = 0.0f;   // stale slot: last read this dir1
        if (lk == 0) v_bf[mycol] = f2bf(v0);
        ubd = ubd_new;
        vbd = vbd_new;
        __syncthreads();   // barrier B: v + SvAcc[p^1] published
    }

    // ---- publish final u, v in f32 for the epilogue ----
    if (lr == 0) {
        f32x4 uf = {u4[0], u4[1], u4[2], u4[3]};
        *reinterpret_cast<f32x4*>(&u_f[r_a0]) = uf;
    }
    if (lk == 0) v_f[mycol] = v0;
    __syncthreads();

    // ================= epilogue =================
    // T = (u*k)*v with identical mul order on both panels -> bitwise-
    // consistent equality tests for mutual argmax.
    float rm;   // rowmax of this lane's row
    {
        const float ur = u_f[myrow];
        float mm = 0.0f;
        #pragma unroll
        for (int t = 0; t < 8; ++t) {
            const f32x4 va = *reinterpret_cast<const f32x4*>(&v_f[32 * t + 8 * lk]);
            const f32x4 vb = *reinterpret_cast<const f32x4*>(&v_f[32 * t + 8 * lk + 4]);
            const float vj[8] = {va[0], va[1], va[2], va[3], vb[0], vb[1], vb[2], vb[3]};
            #pragma unroll
            for (int j = 0; j < 8; ++j) {
                const float tv = ur * bf2f(KA[t][j]) * vj[j];
                mm = fmaxf(mm, tv);
            }
        }
        mm = swz16_maxf(mm);
        mm = fmaxf(mm, __shfl_xor(mm, 32, 64));
        rm = mm;
        if (lk == 0) rm_s[myrow] = mm;
    }
    float cmv;  // colmax of this lane's col
    {
        const float vc = v_f[mycol];
        float mm = 0.0f;
        #pragma unroll
        for (int t = 0; t < 8; ++t) {
            const int rb = 32 * t + 8 * lk;
            const bf8 kb = *reinterpret_cast<const bf8*>(myKTL + t * 512);
            const f32x4 ua = *reinterpret_cast<const f32x4*>(&u_f[rb]);
            const f32x4 ub = *reinterpret_cast<const f32x4*>(&u_f[rb + 4]);
            const float uj[8] = {ua[0], ua[1], ua[2], ua[3], ub[0], ub[1], ub[2], ub[3]};
            #pragma unroll
            for (int j = 0; j < 8; ++j) {
                const float tv = uj[j] * bf2f(kb[j]) * vc;
                mm = fmaxf(mm, tv);
            }
        }
        mm = swz16_maxf(mm);
        mm = fmaxf(mm, __shfl_xor(mm, 32, 64));
        cmv = mm;
        if (lk == 0) cm_s[mycol] = mm;
    }
    __syncthreads();   // rm_s / cm_s published

    float* Ot = out_t + (size_t)b * L_FLAT;
    float* Oa = out_a + (size_t)b * L_FLAT;
    const int stride = nd + 1;

    // births row (col-panel: col-has + write) + corner
    {
        const float vc = v_f[mycol];
        const bool cv = (mycol < nd);
        int has = 0;
        #pragma unroll
        for (int t = 0; t < 8; ++t) {
            const int rb = 32 * t + 8 * lk;
            const bf8 kb = *reinterpret_cast<const bf8*>(myKTL + t * 512);
            const f32x4 ua = *reinterpret_cast<const f32x4*>(&u_f[rb]);
            const f32x4 ub = *reinterpret_cast<const f32x4*>(&u_f[rb + 4]);
            const f32x4 ra = *reinterpret_cast<const f32x4*>(&rm_s[rb]);
            const f32x4 rb4 = *reinterpret_cast<const f32x4*>(&rm_s[rb + 4]);
            const float uj[8] = {ua[0], ua[1], ua[2], ua[3], ub[0], ub[1], ub[2], ub[3]};
            const float rj[8] = {ra[0], ra[1], ra[2], ra[3], rb4[0], rb4[1], rb4[2], rb4[3]};
            #pragma unroll
            for (int j = 0; j < 8; ++j) {
                const int rowj = rb + j;
                const float tv = uj[j] * bf2f(kb[j]) * vc;
                const bool bit = (rowj < nt) && cv && (tv == rj[j]) && (tv == cmv);
                has |= bit ? 1 : 0;
            }
        }
        has = swz16_ori(has);
        has |= __shfl_xor(has, 32, 64);
        if (lk == 0 && cv) {
            const int kk = nt * stride + mycol;
            Ot[kk] = ubd * vc;
            Oa[kk] = has ? 0.0f : 1.0f;
        }
    }
    if (tid == 0) {
        const int kk = nt * stride + nd;
        Ot[kk] = ubd * vbd;
        Oa[kk] = 0.0f;
    }

    // interior + deaths (row-panel, 16B-packed stores per 4-col group)
    {
        const float ur = u_f[myrow];
        const bool rv = (myrow < nt);
        int has = 0;
        #pragma unroll
        for (int t = 0; t < 8; ++t) {
            const int cb = 32 * t + 8 * lk;
            const f32x4 va  = *reinterpret_cast<const f32x4*>(&v_f[cb]);
            const f32x4 vb  = *reinterpret_cast<const f32x4*>(&v_f[cb + 4]);
            const f32x4 ca  = *reinterpret_cast<const f32x4*>(&cm_s[cb]);
            const f32x4 cb4 = *reinterpret_cast<const f32x4*>(&cm_s[cb + 4]);
            float tvs[8];
            float abs_[8];
            #pragma unroll
            for (int j = 0; j < 4; ++j) {
                const float tv = ur * bf2f(KA[t][j]) * va[j];
                const bool bit = rv && ((cb + j) < nd) && (tv == rm) && (tv == ca[j]);
                tvs[j] = tv; abs_[j] = bit ? 1.0f : 0.0f;
                has |= bit ? 1 : 0;
            }
            #pragma unroll
            for (int j = 0; j < 4; ++j) {
                const float tv = ur * bf2f(KA[t][4 + j]) * vb[j];
                const bool bit = rv && ((cb + 4 + j) < nd) && (tv == rm) && (tv == cb4[j]);
                tvs[4 + j] = tv; abs_[4 + j] = bit ? 1.0f : 0.0f;
                has |= bit ? 1 : 0;
            }
            if (rv) {
                float* OtR = Ot + (size_t)myrow * stride;
                float* OaR = Oa + (size_t)myrow * stride;
                #pragma unroll
                for (int g = 0; g < 2; ++g) {
                    const int c0 = cb + 4 * g;
                    if (c0 + 3 < nd) {
                        F4 ot = {tvs[4*g], tvs[4*g+1], tvs[4*g+2], tvs[4*g+3]};
                        F4 oa = {abs_[4*g], abs_[4*g+1], abs_[4*g+2], abs_[4*g+3]};
                        *reinterpret_cast<F4*>(OtR + c0) = ot;
                        *reinterpret_cast<F4*>(OaR + c0) = oa;
                    } else {
                        #pragma unroll
                        for (int j = 0; j < 4; ++j) {
                            if (c0 + j < nd) {
                                OtR[c0 + j] = tvs[4*g + j];
                                OaR[c0 + j] = abs_[4*g + j];
                            }
                        }
                    }
                }
            }
        }
        has = swz16_ori(has);
        has |= __shfl_xor(has, 32, 64);
        if (lk == 0 && rv) {
            const int kk = myrow * stride + nd;
            Ot[kk] = ur * vbd;
            Oa[kk] = has ? 0.0f : 1.0f;
        }
    }

    // zero-fill padding [length, L_FLAT)
    const int length = (nt + 1) * stride;
    for (int k = length + tid; k < L_FLAT; k += 1024) {
        Ot[k] = 0.0f;
        Oa[k] = 0.0f;
    }
}

extern "C" void kernel_launch(void* const* d_in, const int* in_sizes, int n_in,
                              void* d_out, int out_size, void* d_ws, size_t ws_size,
                              hipStream_t stream)
{
    const float* aff  = (const float*)d_in[0];
    const int*   ndet = (const int*)d_in[1];
    const int*   ntrk = (const int*)d_in[2];
    const int    Bn   = in_sizes[1];
    float* out_t = (float*)d_out;
    float* out_a = out_t + (size_t)Bn * L_FLAT;
    assoc_sinkhorn_kernel<<<dim3(Bn), dim3(1024), 0, stream>>>(aff, ndet, ntrk, out_t, out_a);
}